// Round 3
// baseline (496.436 us; speedup 1.0000x reference)
//
#include <hip/hip_runtime.h>
#include <stdint.h>

// ---- problem constants (fixed shapes) ----
#define BTOT   256      // B*T frames
#define LX     197      // tokens incl CLS
#define CDIM   768
#define CADIM  384
#define TFR    8
#define LM1    196      // L-1
#define MTOT   50176    // BTOT*LM1

typedef unsigned short u16;
typedef short          bf16x8 __attribute__((ext_vector_type(8)));
typedef unsigned short u16x8  __attribute__((ext_vector_type(8)));
typedef float          f32x4  __attribute__((ext_vector_type(4)));

typedef const __attribute__((address_space(1))) void gvoid_t;
typedef __attribute__((address_space(3))) void       svoid_t;

static __device__ __forceinline__ u16 f2bf(float f) {
  union { float f; uint32_t u; } v; v.f = f;
  uint32_t u = v.u;
  return (u16)((u + 0x7FFFu + ((u >> 16) & 1u)) >> 16);  // RNE
}
static __device__ __forceinline__ float bf2f(u16 h) {
  union { uint32_t u; float f; } v; v.u = ((uint32_t)h) << 16;
  return v.f;
}

// ---------------- prep: weights bf16 + conv_w transpose ----------------
__global__ void prep_w(const float* __restrict__ W1, const float* __restrict__ W2,
                       const float* __restrict__ cw, u16* __restrict__ w1b,
                       u16* __restrict__ w2b, float* __restrict__ cwT) {
  int i = blockIdx.x * blockDim.x + threadIdx.x;
  if (i < CADIM * CDIM) { w1b[i] = f2bf(W1[i]); w2b[i] = f2bf(W2[i]); }
  if (i < CADIM * 27) {
    int a = i / 27; int tap = i - a * 27;
    cwT[tap * CADIM + a] = cw[i];        // [27][384] channel-contiguous
  }
}

// ---------------- CLS rows: out = x ----------------
__global__ void cls_copy(const float4* __restrict__ x, float4* __restrict__ out) {
  int i = blockIdx.x * blockDim.x + threadIdx.x;   // 256 frames * 192 vec4
  int bt = i / 192;
  int c  = i - bt * 192;
  int idx = bt * (LX * CDIM / 4) + c;              // row 0 of frame bt
  out[idx] = x[idx];
}

// ======================================================================
// fc1: h1[m,a] = x[m,:] . W1[a,:] + b1[a]
//   A staged from fp32 x with inline bf16 convert (padded LDS rows, 72),
//   B staged via global_load_lds(16B) + XOR chunk swizzle (unpadded 64).
//   Epilogue: per-wave LDS transpose -> u16x8 vector stores.
// ======================================================================
__global__ __launch_bounds__(256) void fc1_gemm(
    const float* __restrict__ x,  // fp32 [256*197*768]
    const u16* __restrict__ Bw,   // w1b [384][768] bf16 (N x K row-major)
    const float* __restrict__ bias,
    u16* __restrict__ Hout)       // [50176][384] bf16
{
  __shared__ __align__(16) u16 As[128 * 72];   // padded
  __shared__ __align__(16) u16 Bs[128 * 64];   // swizzled
  const int tid  = threadIdx.x;
  const int lane = tid & 63;
  const int wave = tid >> 6;
  const int m0 = blockIdx.x * 128;
  const int n0 = blockIdx.y * 128;
  const int lm = lane & 15;
  const int lk = lane >> 4;
  const int wm = (wave & 1) * 64;
  const int wn = (wave >> 1) * 64;

  // ---- A staging addresses (fp32 path): thread -> row tid>>1, half tid&1
  const int row2 = tid >> 1;
  const int half = tid & 1;
  int tokA = m0 + row2;
  int btA = tokA / LM1;
  int lA = tokA - btA * LM1;
  const float* arow = x + (size_t)(btA * LX + 1 + lA) * CDIM + half * 32;
  u16* adst = As + row2 * 72 + half * 32;

  // ---- B staging (global_load_lds, XOR swizzle)
  const int srow = lane >> 3;                 // row & 7
  const int cch  = (lane & 7) ^ srow;         // global chunk fetched
  size_t boff[4];
  u16* bsdst[4];
#pragma unroll
  for (int s = 0; s < 4; ++s) {
    int row = wave * 32 + s * 8 + srow;
    boff[s] = (size_t)(n0 + row) * CDIM + cch * 8;
    bsdst[s] = Bs + (wave * 32 + s * 8) * 64;
  }
  const int r7  = lm & 7;
  const int swб0 = ((lk    ) ^ r7) << 3;   // B kk=0
  const int swб1 = ((lk + 4) ^ r7) << 3;   // B kk=32

  f32x4 acc[4][4];
#pragma unroll
  for (int i = 0; i < 4; i++)
#pragma unroll
    for (int j = 0; j < 4; j++) acc[i][j] = (f32x4)0.0f;

  for (int k0 = 0; k0 < CDIM; k0 += 64) {
    // B: async direct-to-LDS
#pragma unroll
    for (int s = 0; s < 4; ++s)
      __builtin_amdgcn_global_load_lds((gvoid_t*)(Bw + boff[s] + k0),
                                       (svoid_t*)bsdst[s], 16, 0, 0);
    // A: fp32 load -> bf16 -> LDS
    {
      float4 v[8];
#pragma unroll
      for (int q = 0; q < 8; ++q)
        v[q] = *(const float4*)(arow + k0 + q * 4);
#pragma unroll
      for (int q = 0; q < 4; ++q) {
        u16x8 o;
        o[0] = f2bf(v[2*q].x);   o[1] = f2bf(v[2*q].y);
        o[2] = f2bf(v[2*q].z);   o[3] = f2bf(v[2*q].w);
        o[4] = f2bf(v[2*q+1].x); o[5] = f2bf(v[2*q+1].y);
        o[6] = f2bf(v[2*q+1].z); o[7] = f2bf(v[2*q+1].w);
        *(u16x8*)(adst + q * 8) = o;
      }
    }
    __syncthreads();
    {
      bf16x8 af[4], bfr[4];
#pragma unroll
      for (int i = 0; i < 4; i++)
        af[i] = *(const bf16x8*)&As[(wm + i * 16 + lm) * 72 + 0 + lk * 8];
#pragma unroll
      for (int j = 0; j < 4; j++)
        bfr[j] = *(const bf16x8*)&Bs[(wn + j * 16 + lm) * 64 + swб0];
#pragma unroll
      for (int i = 0; i < 4; i++)
#pragma unroll
        for (int j = 0; j < 4; j++)
          acc[i][j] = __builtin_amdgcn_mfma_f32_16x16x32_bf16(af[i], bfr[j], acc[i][j], 0, 0, 0);
#pragma unroll
      for (int i = 0; i < 4; i++)
        af[i] = *(const bf16x8*)&As[(wm + i * 16 + lm) * 72 + 32 + lk * 8];
#pragma unroll
      for (int j = 0; j < 4; j++)
        bfr[j] = *(const bf16x8*)&Bs[(wn + j * 16 + lm) * 64 + swб1];
#pragma unroll
      for (int i = 0; i < 4; i++)
#pragma unroll
        for (int j = 0; j < 4; j++)
          acc[i][j] = __builtin_amdgcn_mfma_f32_16x16x32_bf16(af[i], bfr[j], acc[i][j], 0, 0, 0);
    }
    __syncthreads();
  }

  // ---- epilogue: per-wave 16x64 u16 patch in LDS -> u16x8 global stores
  u16* patch = (u16*)As + wave * 16 * 72;     // reuse As, 2304 B/wave
#pragma unroll
  for (int i = 0; i < 4; i++) {
#pragma unroll
    for (int j = 0; j < 4; j++) {
      float bv = bias[n0 + wn + j * 16 + lm];
#pragma unroll
      for (int r = 0; r < 4; r++)
        patch[(lk * 4 + r) * 72 + j * 16 + lm] = f2bf(acc[i][j][r] + bv);
    }
    __syncthreads();
#pragma unroll
    for (int p = 0; p < 2; ++p) {
      int row = (lane >> 3) + p * 8;
      int col = (lane & 7) * 8;
      u16x8 v = *(const u16x8*)(patch + row * 72 + col);
      *(u16x8*)(Hout + (size_t)(m0 + wm + i * 16 + row) * CADIM + n0 + wn + col) = v;
    }
    __syncthreads();
  }
}

// ---------------- depthwise 3x3x3 conv: 2x2 outputs/thread ----------------
__global__ __launch_bounds__(256) void dwconv(
    const u16* __restrict__ h1, const float* __restrict__ cwT,
    const float* __restrict__ cb, u16* __restrict__ h2)
{
  int idx = blockIdx.x * blockDim.x + threadIdx.x;   // < 256*49*48
  int cg = idx % 48;
  int rest = idx / 48;                 // frame*49 + hp*7 + wp
  int wp = rest % 7; rest /= 7;
  int hp = rest % 7; rest /= 7;        // rest = frame = b*8+t
  int t = rest & 7;
  int frame = rest;
  int a0 = cg * 8;
  int h0 = hp * 2, w0 = wp * 2;

  float acc[2][2][8];
#pragma unroll
  for (int c = 0; c < 8; ++c) {
    float bv = cb[a0 + c];
    acc[0][0][c] = bv; acc[0][1][c] = bv; acc[1][0][c] = bv; acc[1][1][c] = bv;
  }

#pragma unroll
  for (int dt = -1; dt <= 1; ++dt) {
    int tt = t + dt;
    if (tt < 0 || tt >= TFR) continue;
    float wreg[9][8];
#pragma unroll
    for (int j = 0; j < 9; ++j) {
      const float* wp8 = cwT + ((dt + 1) * 9 + j) * CADIM + a0;
#pragma unroll
      for (int c = 0; c < 8; ++c) wreg[j][c] = wp8[c];
    }
    const u16* fbase = h1 + (size_t)(frame + dt) * LM1 * CADIM + a0;
#pragma unroll
    for (int ih = 0; ih < 4; ++ih) {
      int hh = h0 - 1 + ih;
      if (hh < 0 || hh >= 14) continue;
#pragma unroll
      for (int iw = 0; iw < 4; ++iw) {
        int ww = w0 - 1 + iw;
        if (ww < 0 || ww >= 14) continue;
        bf16x8 v = *(const bf16x8*)(fbase + (hh * 14 + ww) * CADIM);
        float vf[8];
#pragma unroll
        for (int c = 0; c < 8; ++c) vf[c] = bf2f((u16)v[c]);
#pragma unroll
        for (int oh = 0; oh < 2; ++oh) {
          if (ih - 1 - oh < -1 || ih - 1 - oh > 1) continue;
#pragma unroll
          for (int ow = 0; ow < 2; ++ow) {
            if (iw - 1 - ow < -1 || iw - 1 - ow > 1) continue;
            int j = (ih - oh) * 3 + (iw - ow);
#pragma unroll
            for (int c = 0; c < 8; ++c)
              acc[oh][ow][c] += vf[c] * wreg[j][c];
          }
        }
      }
    }
  }
  const size_t obase = (size_t)frame * LM1 * CADIM + a0;
#pragma unroll
  for (int oh = 0; oh < 2; ++oh)
#pragma unroll
    for (int ow = 0; ow < 2; ++ow) {
      u16x8 o;
#pragma unroll
      for (int c = 0; c < 8; ++c) o[c] = f2bf(acc[oh][ow][c]);
      *(u16x8*)(h2 + obase + ((size_t)(h0 + oh) * 14 + w0 + ow) * CADIM) = o;
    }
}

// ======================================================================
// fc2 + residual: out = x + h2 . W2^T + b2
//   A,B via global_load_lds swizzle; epilogue: per-wave fp32 LDS
//   transpose -> float4 x-read + float4 out-store.
// ======================================================================
__global__ __launch_bounds__(256) void fc2_gemm(
    const u16* __restrict__ A,    // h2 [50176][384] bf16
    const u16* __restrict__ Bw,   // w2b [768][384] bf16 (N x K row-major)
    const float* __restrict__ bias,
    const float* __restrict__ x,
    float* __restrict__ out)
{
  __shared__ __align__(16) u16 As[128 * 64];
  __shared__ __align__(16) u16 Bs[128 * 64];
  const int tid  = threadIdx.x;
  const int lane = tid & 63;
  const int wave = tid >> 6;
  const int m0 = blockIdx.x * 128;
  const int n0 = blockIdx.y * 128;
  const int lm = lane & 15;
  const int lk = lane >> 4;
  const int wm = (wave & 1) * 64;
  const int wn = (wave >> 1) * 64;

  const int srow = lane >> 3;
  const int cch  = (lane & 7) ^ srow;
  size_t aoff[4], boff[4];
  u16 *asdst[4], *bsdst[4];
#pragma unroll
  for (int s = 0; s < 4; ++s) {
    int row = wave * 32 + s * 8 + srow;
    aoff[s] = (size_t)(m0 + row) * CADIM + cch * 8;
    boff[s] = (size_t)(n0 + row) * CADIM + cch * 8;
    asdst[s] = As + (wave * 32 + s * 8) * 64;
    bsdst[s] = Bs + (wave * 32 + s * 8) * 64;
  }
  const int r7  = lm & 7;
  const int sw0 = ((lk    ) ^ r7) << 3;
  const int sw1 = ((lk + 4) ^ r7) << 3;

  f32x4 acc[4][4];
#pragma unroll
  for (int i = 0; i < 4; i++)
#pragma unroll
    for (int j = 0; j < 4; j++) acc[i][j] = (f32x4)0.0f;

  for (int k0 = 0; k0 < CADIM; k0 += 64) {
#pragma unroll
    for (int s = 0; s < 4; ++s) {
      __builtin_amdgcn_global_load_lds((gvoid_t*)(A + aoff[s] + k0),
                                       (svoid_t*)asdst[s], 16, 0, 0);
      __builtin_amdgcn_global_load_lds((gvoid_t*)(Bw + boff[s] + k0),
                                       (svoid_t*)bsdst[s], 16, 0, 0);
    }
    __syncthreads();
    {
      bf16x8 af[4], bfr[4];
#pragma unroll
      for (int i = 0; i < 4; i++)
        af[i] = *(const bf16x8*)&As[(wm + i * 16 + lm) * 64 + sw0];
#pragma unroll
      for (int j = 0; j < 4; j++)
        bfr[j] = *(const bf16x8*)&Bs[(wn + j * 16 + lm) * 64 + sw0];
#pragma unroll
      for (int i = 0; i < 4; i++)
#pragma unroll
        for (int j = 0; j < 4; j++)
          acc[i][j] = __builtin_amdgcn_mfma_f32_16x16x32_bf16(af[i], bfr[j], acc[i][j], 0, 0, 0);
#pragma unroll
      for (int i = 0; i < 4; i++)
        af[i] = *(const bf16x8*)&As[(wm + i * 16 + lm) * 64 + sw1];
#pragma unroll
      for (int j = 0; j < 4; j++)
        bfr[j] = *(const bf16x8*)&Bs[(wn + j * 16 + lm) * 64 + sw1];
#pragma unroll
      for (int i = 0; i < 4; i++)
#pragma unroll
        for (int j = 0; j < 4; j++)
          acc[i][j] = __builtin_amdgcn_mfma_f32_16x16x32_bf16(af[i], bfr[j], acc[i][j], 0, 0, 0);
    }
    __syncthreads();
  }

  // ---- epilogue: per-wave 16x64 fp32 patch (pad 68) -> float4 global ops
  float* patch = (float*)As + wave * 16 * 68;   // 4352 B/wave, reuses As/Bs
  // per-thread read lanes: row lane>>2, cols (lane&3)*16 + q*4
  const int erow = lane >> 2;
  const int ecol = (lane & 3) * 16;
  f32x4 bias4[4];
#pragma unroll
  for (int q = 0; q < 4; ++q)
    bias4[q] = *(const f32x4*)(bias + n0 + wn + ecol + q * 4);

#pragma unroll
  for (int i = 0; i < 4; i++) {
#pragma unroll
    for (int j = 0; j < 4; j++)
#pragma unroll
      for (int r = 0; r < 4; r++)
        patch[(lk * 4 + r) * 68 + j * 16 + lm] = acc[i][j][r];
    __syncthreads();
    int tok = m0 + wm + i * 16 + erow;
    int bt = tok / LM1;
    int l = tok - bt * LM1;
    size_t orow = (size_t)(bt * LX + 1 + l) * CDIM + n0 + wn + ecol;
#pragma unroll
    for (int q = 0; q < 4; ++q) {
      f32x4 v = *(const f32x4*)(patch + erow * 68 + ecol + q * 4);
      f32x4 xv = *(const f32x4*)(x + orow + q * 4);
      f32x4 o = v + xv + bias4[q];
      *(f32x4*)(out + orow + q * 4) = o;
    }
    __syncthreads();
  }
}

// ---------------- launch ----------------
extern "C" void kernel_launch(void* const* d_in, const int* in_sizes, int n_in,
                              void* d_out, int out_size, void* d_ws, size_t ws_size,
                              hipStream_t stream) {
  const float* x  = (const float*)d_in[0];
  const float* W1 = (const float*)d_in[1];
  const float* b1 = (const float*)d_in[2];
  const float* cw = (const float*)d_in[3];
  const float* cb = (const float*)d_in[4];
  const float* W2 = (const float*)d_in[5];
  const float* b2 = (const float*)d_in[6];
  float* out = (float*)d_out;

  char* ws = (char*)d_ws;
  u16*   w1b = (u16*)(ws + 0);              //    589,824 B
  u16*   w2b = (u16*)(ws + 589824);         //    589,824 B
  float* cwT = (float*)(ws + 1179648);      //     41,472 B
  u16*   h1  = (u16*)(ws + 1221120);        // 38,535,168 B
  u16*   h2  = (u16*)(ws + 39756288);       // 38,535,168 B

  prep_w  <<<(CADIM * CDIM + 255) / 256, 256, 0, stream>>>(W1, W2, cw, w1b, w2b, cwT);
  cls_copy<<<(BTOT * 192) / 256, 256, 0, stream>>>((const float4*)x, (float4*)out);
  fc1_gemm<<<dim3(MTOT / 128, CADIM / 128), 256, 0, stream>>>(x, w1b, b1, h1);
  dwconv  <<<(BTOT * 49 * 48) / 256, 256, 0, stream>>>(h1, cwT, cb, h2);
  fc2_gemm<<<dim3(MTOT / 128, CDIM / 128), 256, 0, stream>>>(h2, w2b, b2, x, out);
}